// Round 8
// baseline (1670.121 us; speedup 1.0000x reference)
//
#include <hip/hip_runtime.h>
#include <stdint.h>

// ---------- types ----------
typedef __attribute__((ext_vector_type(8))) short short8;
typedef __attribute__((ext_vector_type(4))) float floatx4;

__device__ inline float bf2f(unsigned short u) {
  union { unsigned int i; float f; } v; v.i = ((unsigned int)u) << 16; return v.f;
}
__device__ inline unsigned short f2bf(float f) {
  union { float f; unsigned int i; } v; v.f = f;
  unsigned int r = v.i + 0x7FFFu + ((v.i >> 16) & 1u);  // round-nearest-even
  return (unsigned short)(r >> 16);
}

// ---------- utility ----------
__global__ void zero_i32(int* __restrict__ p, int n) {
  int i = blockIdx.x * blockDim.x + threadIdx.x;
  if (i < n) p[i] = 0;
}

__global__ void cvt_bf16(const float* __restrict__ x, unsigned short* __restrict__ xb, int n) {
  int i = blockIdx.x * blockDim.x + threadIdx.x;
  if (i < n) xb[i] = f2bf(x[i]);
}

// ---------- tile binning: bin = dst>>4, 8 sub-counters per tile (contention /8) ----
__global__ void count_tile(const int* __restrict__ dst, int* __restrict__ cnt8, int E) {
  int e = blockIdx.x * blockDim.x + threadIdx.x;
  if (e < E) atomicAdd(&cnt8[((dst[e] >> 4) << 3) | (e & 7)], 1);
}

// scatter: rec = (src<<7) | (dst&15)<<3 | rel   (src<2^17, 24 bits total)
__global__ void scatter_tile(const int* __restrict__ src, const int* __restrict__ dst,
                             const int* __restrict__ et, int* __restrict__ pos8,
                             unsigned* __restrict__ rec, int E) {
  int e = blockIdx.x * blockDim.x + threadIdx.x;
  if (e < E) {
    int d = dst[e];
    int p = atomicAdd(&pos8[((d >> 4) << 3) | (e & 7)], 1);
    rec[p] = ((unsigned)src[e] << 7) | ((unsigned)(d & 15) << 3) | (unsigned)et[e];
  }
}

// ---------- exclusive scan of cnt[n] -> eptr[n] (+eptr[n]=total), pos copy ----------
#define SCAN_T 256
#define SCAN_E 16   // 4096 elems per block

__global__ void scan1(const int* __restrict__ cnt, int* __restrict__ bsum, int n) {
  __shared__ int lds[SCAN_T];
  int base = blockIdx.x * (SCAN_T * SCAN_E);
  int tid = threadIdx.x;
  int s = 0;
#pragma unroll
  for (int j = 0; j < SCAN_E; ++j) {
    int i = base + tid * SCAN_E + j;
    if (i < n) s += cnt[i];
  }
  lds[tid] = s; __syncthreads();
  for (int off = SCAN_T / 2; off > 0; off >>= 1) {
    if (tid < off) lds[tid] += lds[tid + off];
    __syncthreads();
  }
  if (tid == 0) bsum[blockIdx.x] = lds[0];
}

__global__ void scan2(int* __restrict__ bsum, int* __restrict__ eptr, int nb, int n) {
  if (threadIdx.x == 0 && blockIdx.x == 0) {
    int run = 0;
    for (int b = 0; b < nb; ++b) { int v = bsum[b]; bsum[b] = run; run += v; }
    eptr[n] = run;
  }
}

__global__ void scan3(const int* __restrict__ cnt, const int* __restrict__ bsum,
                      int* __restrict__ eptr, int* __restrict__ epos, int n) {
  __shared__ int lds[SCAN_T];
  int base = blockIdx.x * (SCAN_T * SCAN_E);
  int tid = threadIdx.x;
  int loc[SCAN_E]; int s = 0;
#pragma unroll
  for (int j = 0; j < SCAN_E; ++j) {
    int i = base + tid * SCAN_E + j;
    loc[j] = (i < n) ? cnt[i] : 0; s += loc[j];
  }
  lds[tid] = s; __syncthreads();
  for (int off = 1; off < SCAN_T; off <<= 1) {   // Hillis-Steele inclusive
    int v = (tid >= off) ? lds[tid - off] : 0;
    __syncthreads();
    lds[tid] += v;
    __syncthreads();
  }
  int run = (tid > 0 ? lds[tid - 1] : 0) + bsum[blockIdx.x];
#pragma unroll
  for (int j = 0; j < SCAN_E; ++j) {
    int i = base + tid * SCAN_E + j;
    if (i < n) { eptr[i] = run; epos[i] = run; run += loc[j]; }
  }
}

// ---------- pre-pack W (8 mats) + root into MFMA B-fragment layout, bf16 ----------
__global__ void prep_wb(const float* __restrict__ W, const float* __restrict__ root,
                        unsigned short* __restrict__ Wb) {
  int idx = blockIdx.x * blockDim.x + threadIdx.x;  // 9*4096
  if (idx >= 9 * 4096) return;
  int j = idx & 7, lane = (idx >> 3) & 63, nt = (idx >> 9) & 3, kc = (idx >> 11) & 1, mat = idx >> 12;
  int k = kc * 32 + (lane >> 4) * 8 + j, c = nt * 16 + (lane & 15);
  float v = (mat < 8) ? W[((size_t)mat * 64 + k) * 64 + c] : root[(size_t)k * 64 + c];
  Wb[idx] = f2bf(v);
}

// ---------- fused per-layer kernel: edge-parallel aggregate via LDS f32 atomics,
// then 18 MFMAs. Block = one 16-dst tile (grid-stride). No per-edge relation VALU:
// seg = rec&127 indexes sumLDS directly; counts accumulated by lane 0.
#define AROW 72
__global__ void __launch_bounds__(256, 3)
fused_layer(const unsigned short* __restrict__ xsrc, const int* __restrict__ tptr,
            const unsigned* __restrict__ rec, const unsigned short* __restrict__ Wb,
            const float* __restrict__ bias, unsigned short* __restrict__ out_bf,
            float* __restrict__ out_f32, int N, int tiles, int relu_out)
{
  __shared__ float sumLDS[128 * 64];            // 32 KB  (seg = local*8+rel)
  __shared__ int   cntLDS[128];
  __shared__ unsigned short aA[144 * AROW];     // 20.25 KB  A-tile, MFMA layout
  const int tid  = threadIdx.x;
  const int lane = tid & 63;
  const int w    = tid >> 6;      // wave id == output col-tile nt
  const int lc   = lane & 15;
  const int quad = lane >> 4;

  for (int t = blockIdx.x; t < tiles; t += gridDim.x) {
    const int nb = t << 4;
    __syncthreads();   // prior iteration's stage-2 reads of aA complete

    // ---- zero accumulators; write root rows (mat 8) ----
    for (int i = tid; i < 128 * 64; i += 256) sumLDS[i] = 0.0f;
    if (tid < 128) cntLDS[tid] = 0;
#pragma unroll
    for (int i = 0; i < 4; ++i) {
      const int m = w * 4 + i;
      const int d = nb + m;
      aA[(128 + m) * AROW + lane] = (d < N) ? xsrc[(size_t)d * 64 + lane] : (unsigned short)0;
    }
    __syncthreads();

    // ---- stage 1: edge-parallel accumulate (8-deep gather pipeline per wave) ----
    const int lo = tptr[t << 3], hi = tptr[(t + 1) << 3];
    for (int base = lo + w * 8; base < hi; base += 32) {
      const int mrem = hi - base;   // >=1
      unsigned rcv[8];
      float    vv[8];
#pragma unroll
      for (int u = 0; u < 8; ++u)
        if (u < mrem) rcv[u] = rec[base + u];        // wave-uniform -> SGPR loads
#pragma unroll
      for (int u = 0; u < 8; ++u)
        if (u < mrem) vv[u] = bf2f(xsrc[(size_t)(rcv[u] >> 7) * 64 + lane]);
#pragma unroll
      for (int u = 0; u < 8; ++u)
        if (u < mrem) {
          const int seg = (int)(rcv[u] & 127u);
          atomicAdd(&sumLDS[seg * 64 + lane], vv[u]);
          if (lane == 0) atomicAdd(&cntLDS[seg], 1);
        }
    }
    __syncthreads();

    // ---- convert sums -> means -> bf16 A rows (row = rel*16 + local) ----
    for (int i = tid; i < 128 * 64; i += 256) {
      const int seg = i >> 6, k = i & 63;
      const int rel = seg & 7, m = seg >> 3;
      const float c = (float)cntLDS[seg];
      const float mean = sumLDS[i] / fmaxf(c, 1.0f);
      aA[(rel * 16 + m) * AROW + k] = f2bf(mean);
    }
    __syncthreads();

    // ---- stage 2: 18 MFMAs; B-frags streamed from L2-hot Wb ----
    floatx4 dacc = {0.f, 0.f, 0.f, 0.f};
#pragma unroll
    for (int mat = 0; mat < 9; ++mat) {
      const short8 a0 = *(const short8*)&aA[(mat * 16 + lc) * AROW + quad * 8];
      const short8 a1 = *(const short8*)&aA[(mat * 16 + lc) * AROW + 32 + quad * 8];
      const short8 b0 = *(const short8*)(Wb + (size_t)((mat * 2 + 0) * 4 + w) * 512 + lane * 8);
      const short8 b1 = *(const short8*)(Wb + (size_t)((mat * 2 + 1) * 4 + w) * 512 + lane * 8);
      dacc = __builtin_amdgcn_mfma_f32_16x16x32_bf16(a0, b0, dacc, 0, 0, 0);
      dacc = __builtin_amdgcn_mfma_f32_16x16x32_bf16(a1, b1, dacc, 0, 0, 0);
    }
    const float bv = bias[w * 16 + lc];
    const int c = w * 16 + lc;
#pragma unroll
    for (int i2 = 0; i2 < 4; ++i2) {
      const int r_ = nb + quad * 4 + i2;
      if (r_ < N) {
        const float vvv = dacc[i2] + bv;
        if (relu_out) out_bf[(size_t)r_ * 64 + c] = f2bf(fmaxf(vvv, 0.f));
        else          out_f32[(size_t)r_ * 64 + c] = vvv;
      }
    }
  }
}

// graph segment boundaries from sorted batch
__global__ void glo_bounds(const int* __restrict__ batch, int* __restrict__ glo,
                           int N, int G) {
  int g = blockIdx.x * blockDim.x + threadIdx.x;
  if (g > G) return;
  if (g == G) { glo[G] = N; return; }
  int lo = 0, hi = N;
  while (lo < hi) { int mid = (lo + hi) >> 1; if (batch[mid] < g) lo = mid + 1; else hi = mid; }
  glo[g] = lo;
}

// fused mean-pool + finalize: one block per graph, contiguous node segment
__global__ void __launch_bounds__(256)
pool(const float* __restrict__ acc, const int* __restrict__ glo,
     float* __restrict__ out, int G)
{
  const int g = blockIdx.x;
  const int lane = threadIdx.x & 63;
  const int w = threadIdx.x >> 6;
  const int lo = glo[g], hi = glo[g + 1];
  float s = 0.f;
  for (int n = lo + w; n < hi; n += 4) s += acc[(size_t)n * 64 + lane];
  __shared__ float red[4][64];
  red[w][lane] = s;
  __syncthreads();
  if (w == 0) {
    float t = red[0][lane] + red[1][lane] + red[2][lane] + red[3][lane];
    out[(size_t)g * 64 + lane] = t / fmaxf((float)(hi - lo), 1.0f);
  }
}

// ---------- launch ----------
extern "C" void kernel_launch(void* const* d_in, const int* in_sizes, int n_in,
                              void* d_out, int out_size, void* d_ws, size_t ws_size,
                              hipStream_t stream)
{
  const float* x     = (const float*)d_in[0];
  const int*   ei    = (const int*)d_in[1];
  const int*   etype = (const int*)d_in[2];
  const int*   batch = (const int*)d_in[3];
  const float* W1    = (const float*)d_in[4];
  const float* root1 = (const float*)d_in[5];
  const float* b1    = (const float*)d_in[6];
  const float* W2    = (const float*)d_in[7];
  const float* root2 = (const float*)d_in[8];
  const float* b2    = (const float*)d_in[9];

  const int N = in_sizes[0] / 64;
  const int E = in_sizes[1] / 2;
  const int G = out_size / 64;
  const int* srcp = ei;
  const int* dstp = ei + E;

  const int tiles = (N + 15) >> 4;
  const int nbin  = tiles * 8;          // 8 sub-counters per tile

  // workspace carve-up (256B aligned), ~60 MB total
  char* ws = (char*)d_ws;
  size_t off = 0;
  auto carve = [&](size_t bytes) -> void* {
    void* p = ws + off; off = (off + bytes + 255) & ~(size_t)255; return p;
  };
  unsigned short* xb    = (unsigned short*)carve((size_t)N * 64 * 2);
  unsigned short* hb    = (unsigned short*)carve((size_t)N * 64 * 2);
  float*          acc   = (float*)carve((size_t)N * 64 * 4);
  int*            cnt8  = (int*)carve((size_t)nbin * 4);
  int*            tptr  = (int*)carve(((size_t)nbin + 1) * 4);
  int*            pos8  = (int*)carve((size_t)nbin * 4);
  unsigned*       rec   = (unsigned*)carve((size_t)E * 4);
  unsigned short* Wb1   = (unsigned short*)carve((size_t)9 * 4096 * 2);
  unsigned short* Wb2   = (unsigned short*)carve((size_t)9 * 4096 * 2);
  int*            bsum  = (int*)carve(1024 * 4);
  int*            glo   = (int*)carve((size_t)(G + 1) * 4);
  (void)ws_size; (void)n_in;

  const int nb_scan = (nbin + SCAN_T * SCAN_E - 1) / (SCAN_T * SCAN_E);
  const int nh = N * 64;

  // ---- tile binning ----
  zero_i32<<<(nbin + 255) / 256, 256, 0, stream>>>(cnt8, nbin);
  count_tile<<<(E + 255) / 256, 256, 0, stream>>>(dstp, cnt8, E);
  scan1<<<nb_scan, SCAN_T, 0, stream>>>(cnt8, bsum, nbin);
  scan2<<<1, 64, 0, stream>>>(bsum, tptr, nb_scan, nbin);
  scan3<<<nb_scan, SCAN_T, 0, stream>>>(cnt8, bsum, tptr, pos8, nbin);
  scatter_tile<<<(E + 255) / 256, 256, 0, stream>>>(srcp, dstp, etype, pos8, rec, E);

  // ---- prep ----
  cvt_bf16<<<(nh + 255) / 256, 256, 0, stream>>>(x, xb, nh);
  prep_wb<<<(9 * 4096 + 255) / 256, 256, 0, stream>>>(W1, root1, Wb1);
  prep_wb<<<(9 * 4096 + 255) / 256, 256, 0, stream>>>(W2, root2, Wb2);
  glo_bounds<<<1, 128, 0, stream>>>(batch, glo, N, G);

  // ---- layer 1 (relu fused, bf16 out) ----
  fused_layer<<<1536, 256, 0, stream>>>(xb, tptr, rec, Wb1, b1, hb,
                                        (float*)nullptr, N, tiles, 1);
  // ---- layer 2 (f32 out for pool) ----
  fused_layer<<<1536, 256, 0, stream>>>(hb, tptr, rec, Wb2, b2,
                                        (unsigned short*)nullptr, acc, N, tiles, 0);

  // ---- global mean pool ----
  pool<<<G, 256, 0, stream>>>(acc, glo, (float*)d_out, G);
}

// Round 9
// 1654.270 us; speedup vs baseline: 1.0096x; 1.0096x over previous
//
#include <hip/hip_runtime.h>
#include <stdint.h>

// ---------- types ----------
typedef __attribute__((ext_vector_type(8))) short short8;
typedef __attribute__((ext_vector_type(4))) float floatx4;

__device__ inline float bf2f(unsigned short u) {
  union { unsigned int i; float f; } v; v.i = ((unsigned int)u) << 16; return v.f;
}
__device__ inline unsigned short f2bf(float f) {
  union { float f; unsigned int i; } v; v.f = f;
  unsigned int r = v.i + 0x7FFFu + ((v.i >> 16) & 1u);  // round-nearest-even
  return (unsigned short)(r >> 16);
}

// ---------- utility ----------
__global__ void zero_i32(int* __restrict__ p, int n) {
  int i = blockIdx.x * blockDim.x + threadIdx.x;
  if (i < n) p[i] = 0;
}

__global__ void cvt_bf16(const float* __restrict__ x, unsigned short* __restrict__ xb, int n) {
  int i = blockIdx.x * blockDim.x + threadIdx.x;
  if (i < n) xb[i] = f2bf(x[i]);
}

// count per (dst,rel): one int atomic per edge (contention avg 2)
__global__ void count_rel(const int* __restrict__ dst, const int* __restrict__ et,
                          int* __restrict__ cnt, int E) {
  int e = blockIdx.x * blockDim.x + threadIdx.x;
  if (e < E) atomicAdd(&cnt[(size_t)dst[e] * 8 + et[e]], 1);
}

// ---------- exclusive scan of cnt[n] -> eptr[n] (+eptr[n]=E), epos copy ----------
#define SCAN_T 256
#define SCAN_E 16   // 4096 elems per block

__global__ void scan1(const int* __restrict__ cnt, int* __restrict__ bsum, int n) {
  __shared__ int lds[SCAN_T];
  int base = blockIdx.x * (SCAN_T * SCAN_E);
  int tid = threadIdx.x;
  int s = 0;
#pragma unroll
  for (int j = 0; j < SCAN_E; ++j) {
    int i = base + tid * SCAN_E + j;
    if (i < n) s += cnt[i];
  }
  lds[tid] = s; __syncthreads();
  for (int off = SCAN_T / 2; off > 0; off >>= 1) {
    if (tid < off) lds[tid] += lds[tid + off];
    __syncthreads();
  }
  if (tid == 0) bsum[blockIdx.x] = lds[0];
}

__global__ void scan2(int* __restrict__ bsum, int* __restrict__ eptr, int nb, int n) {
  if (threadIdx.x == 0 && blockIdx.x == 0) {
    int run = 0;
    for (int b = 0; b < nb; ++b) { int v = bsum[b]; bsum[b] = run; run += v; }
    eptr[n] = run;
  }
}

__global__ void scan3(const int* __restrict__ cnt, const int* __restrict__ bsum,
                      int* __restrict__ eptr, int* __restrict__ epos, int n) {
  __shared__ int lds[SCAN_T];
  int base = blockIdx.x * (SCAN_T * SCAN_E);
  int tid = threadIdx.x;
  int loc[SCAN_E]; int s = 0;
#pragma unroll
  for (int j = 0; j < SCAN_E; ++j) {
    int i = base + tid * SCAN_E + j;
    loc[j] = (i < n) ? cnt[i] : 0; s += loc[j];
  }
  lds[tid] = s; __syncthreads();
  for (int off = 1; off < SCAN_T; off <<= 1) {   // Hillis-Steele inclusive
    int v = (tid >= off) ? lds[tid - off] : 0;
    __syncthreads();
    lds[tid] += v;
    __syncthreads();
  }
  int run = (tid > 0 ? lds[tid - 1] : 0) + bsum[blockIdx.x];
#pragma unroll
  for (int j = 0; j < SCAN_E; ++j) {
    int i = base + tid * SCAN_E + j;
    if (i < n) { eptr[i] = run; epos[i] = run; run += loc[j]; }
  }
}

// scatter edges into (dst,rel)-sorted order; rec = (src<<7) | (rel<<4) | (dst&15)
__global__ void scatter_edges(const int* __restrict__ src, const int* __restrict__ dst,
                              const int* __restrict__ et, int* __restrict__ epos,
                              unsigned* __restrict__ rec, int E) {
  int e = blockIdx.x * blockDim.x + threadIdx.x;
  if (e < E) {
    int d = dst[e], r = et[e];
    int p = atomicAdd(&epos[(size_t)d * 8 + r], 1);
    rec[p] = ((unsigned)src[e] << 7) | ((unsigned)r << 4) | (unsigned)(d & 15);
  }
}

// ---------- pre-pack W (8 mats) + root into MFMA B-fragment layout, bf16 ----------
__global__ void prep_wb(const float* __restrict__ W, const float* __restrict__ root,
                        unsigned short* __restrict__ Wb) {
  int idx = blockIdx.x * blockDim.x + threadIdx.x;  // 9*4096
  if (idx >= 9 * 4096) return;
  int j = idx & 7, lane = (idx >> 3) & 63, nt = (idx >> 9) & 3, kc = (idx >> 11) & 1, mat = idx >> 12;
  int k = kc * 32 + (lane >> 4) * 8 + j, c = nt * 16 + (lane & 15);
  float v = (mat < 8) ? W[((size_t)mat * 64 + k) * 64 + c] : root[(size_t)k * 64 + c];
  Wb[idx] = f2bf(v);
}

// ---------- fused per-layer kernel ----------
// Block = one 16-dst tile (grid-stride). Wave w streams the contiguous merged edge
// range of dsts [nb+w*4, nb+w*4+4): unconditional 8-wide body (8 gathers in flight),
// one fire-and-forget ds_add_f32 per edge into sumF[seg][lane] (seg = rec&127 =
// rel*16+local, wave-disjoint rows -> no contention, 2-way bank = free).
// Means converted to bf16 A-tile IN PLACE (regs -> sync -> rewrite) to keep LDS at
// ~35.6 KB -> 4 blocks/CU. Then 18 MFMAs (B-frags streamed from L2-hot Wb).
#define AROW 72
__global__ void __launch_bounds__(256, 4)
fused_layer(const unsigned short* __restrict__ xsrc, const int* __restrict__ eptr,
            const unsigned* __restrict__ rec, const unsigned short* __restrict__ Wb,
            const float* __restrict__ bias, unsigned short* __restrict__ out_bf,
            float* __restrict__ out_f32, int N, int tiles, int relu_out)
{
  __shared__ float sumF[128 * 64];              // 32 KB, aliased as bf16 A-tile
  __shared__ unsigned short rootA[16 * AROW];   // 2.25 KB
  __shared__ float invL[128];
  unsigned short* aA = (unsigned short*)sumF;

  const int tid  = threadIdx.x;
  const int lane = tid & 63;
  const int w    = tid >> 6;      // wave id == output col-tile nt
  const int lc   = lane & 15;
  const int quad = lane >> 4;
  const float bv = bias[w * 16 + lc];

  for (int t = blockIdx.x; t < tiles; t += gridDim.x) {
    const int nb = t << 4;
    __syncthreads();   // prior iteration's stage-2 reads complete before zeroing

    // zero sums (float4), root rows, inv weights
    for (int i = tid; i < 128 * 16; i += 256)
      ((floatx4*)sumF)[i] = (floatx4){0.f, 0.f, 0.f, 0.f};
    for (int i = tid; i < 16 * 64; i += 256) {
      const int m = i >> 6, k = i & 63;
      const int d = nb + m;
      rootA[m * AROW + k] = (d < N) ? xsrc[(size_t)d * 64 + k] : (unsigned short)0;
    }
    if (tid < 128) {
      const int local = tid & 15, rel = tid >> 4;  // tid == seg
      const int d = nb + local;
      int c = 0;
      if (d < N) { const int gi = d * 8 + rel; c = eptr[gi + 1] - eptr[gi]; }
      invL[tid] = 1.0f / fmaxf((float)c, 1.0f);
    }
    __syncthreads();

    // ---- stage 1: wave-parallel edge streaming, 8-deep gather pipeline ----
    const int d0 = min(nb + w * 4, N);
    const int d1 = min(d0 + 4, N);
    const int lo = eptr[d0 * 8], hi = eptr[d1 * 8];
    int e = lo;
    for (; e + 8 <= hi; e += 8) {
      unsigned rc[8]; float v[8];
#pragma unroll
      for (int u = 0; u < 8; ++u) rc[u] = rec[e + u];
#pragma unroll
      for (int u = 0; u < 8; ++u) v[u] = bf2f(xsrc[(size_t)(rc[u] >> 7) * 64 + lane]);
#pragma unroll
      for (int u = 0; u < 8; ++u)
        atomicAdd(&sumF[(rc[u] & 127u) * 64 + lane], v[u]);
    }
    for (; e < hi; ++e) {
      const unsigned rc = rec[e];
      atomicAdd(&sumF[(rc & 127u) * 64 + lane], bf2f(xsrc[(size_t)(rc >> 7) * 64 + lane]));
    }
    __syncthreads();

    // ---- in-place sums -> means(bf16 A rows); conflict-free b32 pattern ----
    float mv[32];
#pragma unroll
    for (int j = 0; j < 32; ++j) {
      const int idx = j * 256 + tid;
      mv[j] = sumF[idx] * invL[idx >> 6];
    }
    __syncthreads();
#pragma unroll
    for (int j = 0; j < 32; ++j) {
      const int idx = j * 256 + tid;
      aA[(idx >> 6) * AROW + (idx & 63)] = f2bf(mv[j]);
    }
    __syncthreads();

    // ---- stage 2: 18 MFMAs ----
    floatx4 dacc = {0.f, 0.f, 0.f, 0.f};
#pragma unroll
    for (int mat = 0; mat < 9; ++mat) {
      short8 a0, a1;
      if (mat < 8) {
        a0 = *(const short8*)&aA[(mat * 16 + lc) * AROW + quad * 8];
        a1 = *(const short8*)&aA[(mat * 16 + lc) * AROW + 32 + quad * 8];
      } else {
        a0 = *(const short8*)&rootA[lc * AROW + quad * 8];
        a1 = *(const short8*)&rootA[lc * AROW + 32 + quad * 8];
      }
      const short8 b0 = *(const short8*)(Wb + (size_t)((mat * 2 + 0) * 4 + w) * 512 + lane * 8);
      const short8 b1 = *(const short8*)(Wb + (size_t)((mat * 2 + 1) * 4 + w) * 512 + lane * 8);
      dacc = __builtin_amdgcn_mfma_f32_16x16x32_bf16(a0, b0, dacc, 0, 0, 0);
      dacc = __builtin_amdgcn_mfma_f32_16x16x32_bf16(a1, b1, dacc, 0, 0, 0);
    }
    const int c = w * 16 + lc;
#pragma unroll
    for (int i2 = 0; i2 < 4; ++i2) {
      const int r_ = nb + quad * 4 + i2;
      if (r_ < N) {
        const float vvv = dacc[i2] + bv;
        if (relu_out) out_bf[(size_t)r_ * 64 + c] = f2bf(fmaxf(vvv, 0.f));
        else          out_f32[(size_t)r_ * 64 + c] = vvv;
      }
    }
  }
}

// graph segment boundaries from sorted batch
__global__ void glo_bounds(const int* __restrict__ batch, int* __restrict__ glo,
                           int N, int G) {
  int g = blockIdx.x * blockDim.x + threadIdx.x;
  if (g > G) return;
  if (g == G) { glo[G] = N; return; }
  int lo = 0, hi = N;
  while (lo < hi) { int mid = (lo + hi) >> 1; if (batch[mid] < g) lo = mid + 1; else hi = mid; }
  glo[g] = lo;
}

// fused mean-pool + finalize: one block per graph, contiguous node segment
__global__ void __launch_bounds__(256)
pool(const float* __restrict__ acc, const int* __restrict__ glo,
     float* __restrict__ out, int G)
{
  const int g = blockIdx.x;
  const int lane = threadIdx.x & 63;
  const int w = threadIdx.x >> 6;
  const int lo = glo[g], hi = glo[g + 1];
  float s = 0.f;
  for (int n = lo + w; n < hi; n += 4) s += acc[(size_t)n * 64 + lane];
  __shared__ float red[4][64];
  red[w][lane] = s;
  __syncthreads();
  if (w == 0) {
    float t = red[0][lane] + red[1][lane] + red[2][lane] + red[3][lane];
    out[(size_t)g * 64 + lane] = t / fmaxf((float)(hi - lo), 1.0f);
  }
}

// ---------- launch ----------
extern "C" void kernel_launch(void* const* d_in, const int* in_sizes, int n_in,
                              void* d_out, int out_size, void* d_ws, size_t ws_size,
                              hipStream_t stream)
{
  const float* x     = (const float*)d_in[0];
  const int*   ei    = (const int*)d_in[1];
  const int*   etype = (const int*)d_in[2];
  const int*   batch = (const int*)d_in[3];
  const float* W1    = (const float*)d_in[4];
  const float* root1 = (const float*)d_in[5];
  const float* b1    = (const float*)d_in[6];
  const float* W2    = (const float*)d_in[7];
  const float* root2 = (const float*)d_in[8];
  const float* b2    = (const float*)d_in[9];

  const int N = in_sizes[0] / 64;
  const int E = in_sizes[1] / 2;
  const int G = out_size / 64;
  const int* srcp = ei;
  const int* dstp = ei + E;

  // workspace carve-up (256B aligned), ~40 MB total
  char* ws = (char*)d_ws;
  size_t off = 0;
  auto carve = [&](size_t bytes) -> void* {
    void* p = ws + off; off = (off + bytes + 255) & ~(size_t)255; return p;
  };
  unsigned short* xb    = (unsigned short*)carve((size_t)N * 64 * 2);
  unsigned short* hb    = (unsigned short*)carve((size_t)N * 64 * 2);
  float*          acc   = (float*)carve((size_t)N * 64 * 4);
  int*            cnt   = (int*)carve((size_t)N * 8 * 4);
  int*            eptr  = (int*)carve(((size_t)N * 8 + 1) * 4);
  int*            epos  = (int*)carve((size_t)N * 8 * 4);
  unsigned*       rec   = (unsigned*)carve((size_t)E * 4);
  unsigned short* Wb1   = (unsigned short*)carve((size_t)9 * 4096 * 2);
  unsigned short* Wb2   = (unsigned short*)carve((size_t)9 * 4096 * 2);
  int*            bsum  = (int*)carve(1024 * 4);
  int*            glo   = (int*)carve((size_t)(G + 1) * 4);
  (void)ws_size; (void)n_in;

  const int nseg = N * 8;
  const int nb_scan = (nseg + SCAN_T * SCAN_E - 1) / (SCAN_T * SCAN_E);
  const int nh = N * 64;
  const int tiles = (N + 15) >> 4;

  // ---- CSR build by (dst,rel) ----
  zero_i32<<<(nseg + 255) / 256, 256, 0, stream>>>(cnt, nseg);
  count_rel<<<(E + 255) / 256, 256, 0, stream>>>(dstp, etype, cnt, E);
  scan1<<<nb_scan, SCAN_T, 0, stream>>>(cnt, bsum, nseg);
  scan2<<<1, 64, 0, stream>>>(bsum, eptr, nb_scan, nseg);
  scan3<<<nb_scan, SCAN_T, 0, stream>>>(cnt, bsum, eptr, epos, nseg);
  scatter_edges<<<(E + 255) / 256, 256, 0, stream>>>(srcp, dstp, etype, epos, rec, E);

  // ---- prep ----
  cvt_bf16<<<(nh + 255) / 256, 256, 0, stream>>>(x, xb, nh);
  prep_wb<<<(9 * 4096 + 255) / 256, 256, 0, stream>>>(W1, root1, Wb1);
  prep_wb<<<(9 * 4096 + 255) / 256, 256, 0, stream>>>(W2, root2, Wb2);
  glo_bounds<<<1, 128, 0, stream>>>(batch, glo, N, G);

  // ---- layer 1 (relu fused, bf16 out) ----
  fused_layer<<<2048, 256, 0, stream>>>(xb, eptr, rec, Wb1, b1, hb,
                                        (float*)nullptr, N, tiles, 1);
  // ---- layer 2 (f32 out for pool) ----
  fused_layer<<<2048, 256, 0, stream>>>(hb, eptr, rec, Wb2, b2,
                                        (unsigned short*)nullptr, acc, N, tiles, 0);

  // ---- global mean pool ----
  pool<<<G, 256, 0, stream>>>(acc, glo, (float*)d_out, G);
}

// Round 10
// 1634.270 us; speedup vs baseline: 1.0219x; 1.0122x over previous
//
#include <hip/hip_runtime.h>
#include <stdint.h>

// ---------- types ----------
typedef __attribute__((ext_vector_type(8))) short short8;
typedef __attribute__((ext_vector_type(4))) float floatx4;

__device__ inline float bf2f(unsigned short u) {
  union { unsigned int i; float f; } v; v.i = ((unsigned int)u) << 16; return v.f;
}
__device__ inline unsigned short f2bf(float f) {
  union { float f; unsigned int i; } v; v.f = f;
  unsigned int r = v.i + 0x7FFFu + ((v.i >> 16) & 1u);  // round-nearest-even
  return (unsigned short)(r >> 16);
}

// ---------- utility ----------
__global__ void zero_i32(int* __restrict__ p, int n) {
  int i = blockIdx.x * blockDim.x + threadIdx.x;
  if (i < n) p[i] = 0;
}

__global__ void cvt_bf16(const float* __restrict__ x, unsigned short* __restrict__ xb, int n) {
  int i = blockIdx.x * blockDim.x + threadIdx.x;
  if (i < n) xb[i] = f2bf(x[i]);
}

// count per (dst,rel): one int atomic per edge (contention avg 2)
__global__ void count_rel(const int* __restrict__ dst, const int* __restrict__ et,
                          int* __restrict__ cnt, int E) {
  int e = blockIdx.x * blockDim.x + threadIdx.x;
  if (e < E) atomicAdd(&cnt[(size_t)dst[e] * 8 + et[e]], 1);
}

// ---------- exclusive scan of cnt[n] -> eptr[n] (+eptr[n]=E), epos copy ----------
#define SCAN_T 256
#define SCAN_E 16   // 4096 elems per block

__global__ void scan1(const int* __restrict__ cnt, int* __restrict__ bsum, int n) {
  __shared__ int lds[SCAN_T];
  int base = blockIdx.x * (SCAN_T * SCAN_E);
  int tid = threadIdx.x;
  int s = 0;
#pragma unroll
  for (int j = 0; j < SCAN_E; ++j) {
    int i = base + tid * SCAN_E + j;
    if (i < n) s += cnt[i];
  }
  lds[tid] = s; __syncthreads();
  for (int off = SCAN_T / 2; off > 0; off >>= 1) {
    if (tid < off) lds[tid] += lds[tid + off];
    __syncthreads();
  }
  if (tid == 0) bsum[blockIdx.x] = lds[0];
}

__global__ void scan2(int* __restrict__ bsum, int* __restrict__ eptr, int nb, int n) {
  if (threadIdx.x == 0 && blockIdx.x == 0) {
    int run = 0;
    for (int b = 0; b < nb; ++b) { int v = bsum[b]; bsum[b] = run; run += v; }
    eptr[n] = run;
  }
}

__global__ void scan3(const int* __restrict__ cnt, const int* __restrict__ bsum,
                      int* __restrict__ eptr, int* __restrict__ epos, int n) {
  __shared__ int lds[SCAN_T];
  int base = blockIdx.x * (SCAN_T * SCAN_E);
  int tid = threadIdx.x;
  int loc[SCAN_E]; int s = 0;
#pragma unroll
  for (int j = 0; j < SCAN_E; ++j) {
    int i = base + tid * SCAN_E + j;
    loc[j] = (i < n) ? cnt[i] : 0; s += loc[j];
  }
  lds[tid] = s; __syncthreads();
  for (int off = 1; off < SCAN_T; off <<= 1) {   // Hillis-Steele inclusive
    int v = (tid >= off) ? lds[tid - off] : 0;
    __syncthreads();
    lds[tid] += v;
    __syncthreads();
  }
  int run = (tid > 0 ? lds[tid - 1] : 0) + bsum[blockIdx.x];
#pragma unroll
  for (int j = 0; j < SCAN_E; ++j) {
    int i = base + tid * SCAN_E + j;
    if (i < n) { eptr[i] = run; epos[i] = run; run += loc[j]; }
  }
}

// scatter edges into (dst,rel)-sorted order; rec = (src<<7) | (rel<<4) | (dst&15)
__global__ void scatter_edges(const int* __restrict__ src, const int* __restrict__ dst,
                              const int* __restrict__ et, int* __restrict__ epos,
                              unsigned* __restrict__ rec, int E) {
  int e = blockIdx.x * blockDim.x + threadIdx.x;
  if (e < E) {
    int d = dst[e], r = et[e];
    int p = atomicAdd(&epos[(size_t)d * 8 + r], 1);
    rec[p] = ((unsigned)src[e] << 7) | ((unsigned)r << 4) | (unsigned)(d & 15);
  }
}

// ---------- pre-pack W (8 mats) + root into MFMA B-fragment layout, bf16 ----------
__global__ void prep_wb(const float* __restrict__ W, const float* __restrict__ root,
                        unsigned short* __restrict__ Wb) {
  int idx = blockIdx.x * blockDim.x + threadIdx.x;  // 9*4096
  if (idx >= 9 * 4096) return;
  int j = idx & 7, lane = (idx >> 3) & 63, nt = (idx >> 9) & 3, kc = (idx >> 11) & 1, mat = idx >> 12;
  int k = kc * 32 + (lane >> 4) * 8 + j, c = nt * 16 + (lane & 15);
  float v = (mat < 8) ? W[((size_t)mat * 64 + k) * 64 + c] : root[(size_t)k * 64 + c];
  Wb[idx] = f2bf(v);
}

// ---------- fused per-layer kernel ----------
// Block = one 16-dst tile (grid-stride). Wave w streams the contiguous merged edge
// range of dsts [nb+w*4, nb+w*4+4): unconditional 8-wide body (8 gathers in flight),
// one fire-and-forget ds_add_f32 per edge into sumF[seg][lane] (seg = rec&127 =
// rel*16+local, wave-disjoint rows -> no contention, 2-way bank = free).
// Sums -> bf16 A-tile converted IN PLACE in 4 chunks of 8 regs (no spill; chunk ch
// writes land below all later-chunk reads: 1152ch+1148 < 2048(ch+1), verified).
#define AROW 72
__global__ void __launch_bounds__(256, 4)
fused_layer(const unsigned short* __restrict__ xsrc, const int* __restrict__ eptr,
            const unsigned* __restrict__ rec, const unsigned short* __restrict__ Wb,
            const float* __restrict__ bias, unsigned short* __restrict__ out_bf,
            float* __restrict__ out_f32, int N, int tiles, int relu_out)
{
  __shared__ float sumF[128 * 64];              // 32 KB, aliased as bf16 A-tile
  __shared__ unsigned short rootA[16 * AROW];   // 2.25 KB
  __shared__ float invL[128];
  unsigned short* aA = (unsigned short*)sumF;

  const int tid  = threadIdx.x;
  const int lane = tid & 63;
  const int w    = tid >> 6;      // wave id == output col-tile nt
  const int lc   = lane & 15;
  const int quad = lane >> 4;
  const float bv = bias[w * 16 + lc];

  for (int t = blockIdx.x; t < tiles; t += gridDim.x) {
    const int nb = t << 4;
    __syncthreads();   // prior iteration's stage-2 reads complete before zeroing

    // zero sums (float4), root rows, inv weights
    for (int i = tid; i < 128 * 16; i += 256)
      ((floatx4*)sumF)[i] = (floatx4){0.f, 0.f, 0.f, 0.f};
    for (int i = tid; i < 16 * 64; i += 256) {
      const int m = i >> 6, k = i & 63;
      const int d = nb + m;
      rootA[m * AROW + k] = (d < N) ? xsrc[(size_t)d * 64 + k] : (unsigned short)0;
    }
    if (tid < 128) {
      const int local = tid & 15, rel = tid >> 4;  // tid == seg
      const int d = nb + local;
      int c = 0;
      if (d < N) { const int gi = d * 8 + rel; c = eptr[gi + 1] - eptr[gi]; }
      invL[tid] = 1.0f / fmaxf((float)c, 1.0f);
    }
    __syncthreads();

    // ---- stage 1: wave-parallel edge streaming, 8-deep gather pipeline ----
    const int d0 = min(nb + w * 4, N);
    const int d1 = min(d0 + 4, N);
    const int lo = eptr[d0 * 8], hi = eptr[d1 * 8];
    int e = lo;
    for (; e + 8 <= hi; e += 8) {
      unsigned rc[8]; float v[8];
#pragma unroll
      for (int u = 0; u < 8; ++u) rc[u] = rec[e + u];
#pragma unroll
      for (int u = 0; u < 8; ++u) v[u] = bf2f(xsrc[(size_t)(rc[u] >> 7) * 64 + lane]);
#pragma unroll
      for (int u = 0; u < 8; ++u)
        atomicAdd(&sumF[(rc[u] & 127u) * 64 + lane], v[u]);
    }
    for (; e < hi; ++e) {
      const unsigned rc = rec[e];
      atomicAdd(&sumF[(rc & 127u) * 64 + lane], bf2f(xsrc[(size_t)(rc >> 7) * 64 + lane]));
    }
    __syncthreads();

    // ---- in-place sums -> means(bf16 A rows), 4 chunks x 8 regs (no spill) ----
#pragma unroll
    for (int ch = 0; ch < 4; ++ch) {
      float mv[8];
#pragma unroll
      for (int j = 0; j < 8; ++j) {
        const int idx = (ch * 8 + j) * 256 + tid;
        mv[j] = sumF[idx] * invL[idx >> 6];
      }
      __syncthreads();
#pragma unroll
      for (int j = 0; j < 8; ++j) {
        const int idx = (ch * 8 + j) * 256 + tid;
        aA[(idx >> 6) * AROW + (idx & 63)] = f2bf(mv[j]);
      }
      __syncthreads();
    }

    // ---- stage 2: 18 MFMAs ----
    floatx4 dacc = {0.f, 0.f, 0.f, 0.f};
#pragma unroll
    for (int mat = 0; mat < 9; ++mat) {
      short8 a0, a1;
      if (mat < 8) {
        a0 = *(const short8*)&aA[(mat * 16 + lc) * AROW + quad * 8];
        a1 = *(const short8*)&aA[(mat * 16 + lc) * AROW + 32 + quad * 8];
      } else {
        a0 = *(const short8*)&rootA[lc * AROW + quad * 8];
        a1 = *(const short8*)&rootA[lc * AROW + 32 + quad * 8];
      }
      const short8 b0 = *(const short8*)(Wb + (size_t)((mat * 2 + 0) * 4 + w) * 512 + lane * 8);
      const short8 b1 = *(const short8*)(Wb + (size_t)((mat * 2 + 1) * 4 + w) * 512 + lane * 8);
      dacc = __builtin_amdgcn_mfma_f32_16x16x32_bf16(a0, b0, dacc, 0, 0, 0);
      dacc = __builtin_amdgcn_mfma_f32_16x16x32_bf16(a1, b1, dacc, 0, 0, 0);
    }
    const int c = w * 16 + lc;
#pragma unroll
    for (int i2 = 0; i2 < 4; ++i2) {
      const int r_ = nb + quad * 4 + i2;
      if (r_ < N) {
        const float vvv = dacc[i2] + bv;
        if (relu_out) out_bf[(size_t)r_ * 64 + c] = f2bf(fmaxf(vvv, 0.f));
        else          out_f32[(size_t)r_ * 64 + c] = vvv;
      }
    }
  }
}

// graph segment boundaries from sorted batch
__global__ void glo_bounds(const int* __restrict__ batch, int* __restrict__ glo,
                           int N, int G) {
  int g = blockIdx.x * blockDim.x + threadIdx.x;
  if (g > G) return;
  if (g == G) { glo[G] = N; return; }
  int lo = 0, hi = N;
  while (lo < hi) { int mid = (lo + hi) >> 1; if (batch[mid] < g) lo = mid + 1; else hi = mid; }
  glo[g] = lo;
}

// fused mean-pool + finalize: one block per graph, contiguous node segment
__global__ void __launch_bounds__(256)
pool(const float* __restrict__ acc, const int* __restrict__ glo,
     float* __restrict__ out, int G)
{
  const int g = blockIdx.x;
  const int lane = threadIdx.x & 63;
  const int w = threadIdx.x >> 6;
  const int lo = glo[g], hi = glo[g + 1];
  float s = 0.f;
  for (int n = lo + w; n < hi; n += 4) s += acc[(size_t)n * 64 + lane];
  __shared__ float red[4][64];
  red[w][lane] = s;
  __syncthreads();
  if (w == 0) {
    float t = red[0][lane] + red[1][lane] + red[2][lane] + red[3][lane];
    out[(size_t)g * 64 + lane] = t / fmaxf((float)(hi - lo), 1.0f);
  }
}

// ---------- launch ----------
extern "C" void kernel_launch(void* const* d_in, const int* in_sizes, int n_in,
                              void* d_out, int out_size, void* d_ws, size_t ws_size,
                              hipStream_t stream)
{
  const float* x     = (const float*)d_in[0];
  const int*   ei    = (const int*)d_in[1];
  const int*   etype = (const int*)d_in[2];
  const int*   batch = (const int*)d_in[3];
  const float* W1    = (const float*)d_in[4];
  const float* root1 = (const float*)d_in[5];
  const float* b1    = (const float*)d_in[6];
  const float* W2    = (const float*)d_in[7];
  const float* root2 = (const float*)d_in[8];
  const float* b2    = (const float*)d_in[9];

  const int N = in_sizes[0] / 64;
  const int E = in_sizes[1] / 2;
  const int G = out_size / 64;
  const int* srcp = ei;
  const int* dstp = ei + E;

  // workspace carve-up (256B aligned), ~40 MB total
  char* ws = (char*)d_ws;
  size_t off = 0;
  auto carve = [&](size_t bytes) -> void* {
    void* p = ws + off; off = (off + bytes + 255) & ~(size_t)255; return p;
  };
  unsigned short* xb    = (unsigned short*)carve((size_t)N * 64 * 2);
  unsigned short* hb    = (unsigned short*)carve((size_t)N * 64 * 2);
  float*          acc   = (float*)carve((size_t)N * 64 * 4);
  int*            cnt   = (int*)carve((size_t)N * 8 * 4);
  int*            eptr  = (int*)carve(((size_t)N * 8 + 1) * 4);
  int*            epos  = (int*)carve((size_t)N * 8 * 4);
  unsigned*       rec   = (unsigned*)carve((size_t)E * 4);
  unsigned short* Wb1   = (unsigned short*)carve((size_t)9 * 4096 * 2);
  unsigned short* Wb2   = (unsigned short*)carve((size_t)9 * 4096 * 2);
  int*            bsum  = (int*)carve(1024 * 4);
  int*            glo   = (int*)carve((size_t)(G + 1) * 4);
  (void)ws_size; (void)n_in;

  const int nseg = N * 8;
  const int nb_scan = (nseg + SCAN_T * SCAN_E - 1) / (SCAN_T * SCAN_E);
  const int nh = N * 64;
  const int tiles = (N + 15) >> 4;

  // ---- CSR build by (dst,rel) ----
  zero_i32<<<(nseg + 255) / 256, 256, 0, stream>>>(cnt, nseg);
  count_rel<<<(E + 255) / 256, 256, 0, stream>>>(dstp, etype, cnt, E);
  scan1<<<nb_scan, SCAN_T, 0, stream>>>(cnt, bsum, nseg);
  scan2<<<1, 64, 0, stream>>>(bsum, eptr, nb_scan, nseg);
  scan3<<<nb_scan, SCAN_T, 0, stream>>>(cnt, bsum, eptr, epos, nseg);
  scatter_edges<<<(E + 255) / 256, 256, 0, stream>>>(srcp, dstp, etype, epos, rec, E);

  // ---- prep ----
  cvt_bf16<<<(nh + 255) / 256, 256, 0, stream>>>(x, xb, nh);
  prep_wb<<<(9 * 4096 + 255) / 256, 256, 0, stream>>>(W1, root1, Wb1);
  prep_wb<<<(9 * 4096 + 255) / 256, 256, 0, stream>>>(W2, root2, Wb2);
  glo_bounds<<<1, 128, 0, stream>>>(batch, glo, N, G);

  // ---- layer 1 (relu fused, bf16 out) ----
  fused_layer<<<2048, 256, 0, stream>>>(xb, eptr, rec, Wb1, b1, hb,
                                        (float*)nullptr, N, tiles, 1);
  // ---- layer 2 (f32 out for pool) ----
  fused_layer<<<2048, 256, 0, stream>>>(hb, eptr, rec, Wb2, b2,
                                        (unsigned short*)nullptr, acc, N, tiles, 0);

  // ---- global mean pool ----
  pool<<<G, 256, 0, stream>>>(acc, glo, (float*)d_out, G);
}